// Round 6
// baseline (587.291 us; speedup 1.0000x reference)
//
#include <hip/hip_runtime.h>
#include <hip/hip_bf16.h>

#define T_TOK 4096
#define DM 1024
#define DH 4096
#define NE 8
#define NSLOT (T_TOK * 2)
#define WELEMS ((size_t)NE * DH * DM)

typedef __attribute__((ext_vector_type(4))) float fl4;
typedef __attribute__((ext_vector_type(8))) short sh8;
typedef __attribute__((ext_vector_type(8))) unsigned short us8;
typedef unsigned short u16;

__device__ __forceinline__ u16 f2bf(float f) {
  __hip_bfloat16 h = __float2bfloat16(f);
  return __builtin_bit_cast(u16, h);
}

__device__ __forceinline__ float gelu_tanh(float x) {
  float x3 = x * x * x;
  float u = 0.7978845608028654f * (x + 0.044715f * x3);
  return 0.5f * x * (1.0f + tanhf(u));
}

__device__ __forceinline__ void gload_lds16(const void* g, void* l) {
  __builtin_amdgcn_global_load_lds(
      (const __attribute__((address_space(1))) unsigned int*)g,
      (__attribute__((address_space(3))) unsigned int*)l, 16, 0, 0);
}

// ---------------- weight fp32 -> bf16 ----------------
__global__ __launch_bounds__(256) void wconv_kernel(
    const float* __restrict__ w1, const float* __restrict__ w2,
    u16* __restrict__ w1b, u16* __restrict__ w2b) {
  size_t stride = (size_t)gridDim.x * 256 * 8;
  for (size_t i = ((size_t)blockIdx.x * 256 + threadIdx.x) * 8; i < WELEMS; i += stride) {
    fl4 a0 = *(const fl4*)(w1 + i);
    fl4 a1 = *(const fl4*)(w1 + i + 4);
    fl4 b0 = *(const fl4*)(w2 + i);
    fl4 b1 = *(const fl4*)(w2 + i + 4);
    us8 oa, ob;
#pragma unroll
    for (int j = 0; j < 4; j++) {
      oa[j] = f2bf(a0[j]); oa[j + 4] = f2bf(a1[j]);
      ob[j] = f2bf(b0[j]); ob[j + 4] = f2bf(b1[j]);
    }
    *(us8*)(w1b + i) = oa;
    *(us8*)(w2b + i) = ob;
  }
}

// ---------------- router ----------------
__global__ __launch_bounds__(256) void router_kernel(
    const float* __restrict__ x, const float* __restrict__ rw,
    u16* __restrict__ xbf, int* __restrict__ tok_e, float* __restrict__ tok_w,
    int* __restrict__ ctl) {
  int tid = threadIdx.x;
  int wv = tid >> 6, lane = tid & 63;
  int t = blockIdx.x * 4 + wv;
  if (t >= T_TOK) return;

  const float* xp = x + (size_t)t * DM + lane * 16;
  fl4 xq[4];
#pragma unroll
  for (int i = 0; i < 4; i++) xq[i] = *(const fl4*)(xp + i * 4);

  float acc8[NE];
#pragma unroll
  for (int e = 0; e < NE; e++) {
    const float* wp = rw + (size_t)e * DM + lane * 16;
    float s = 0.f;
#pragma unroll
    for (int i = 0; i < 4; i++) {
      fl4 w4 = *(const fl4*)(wp + i * 4);
      s += xq[i][0] * w4[0] + xq[i][1] * w4[1] + xq[i][2] * w4[2] + xq[i][3] * w4[3];
    }
    acc8[e] = s;
  }
  us8 h0, h1;
#pragma unroll
  for (int i = 0; i < 8; i++) {
    h0[i] = f2bf(xq[i >> 2][i & 3]);
    h1[i] = f2bf(xq[2 + (i >> 2)][i & 3]);
  }
  *(us8*)(xbf + (size_t)t * DM + lane * 16) = h0;
  *(us8*)(xbf + (size_t)t * DM + lane * 16 + 8) = h1;

#pragma unroll
  for (int e = 0; e < NE; e++) {
#pragma unroll
    for (int off = 32; off > 0; off >>= 1) acc8[e] += __shfl_xor(acc8[e], off);
  }

  if (lane == 0) {
    float v1 = -1e30f, v2 = -1e30f;
    int i1 = 0, i2 = 0;
#pragma unroll
    for (int e = 0; e < NE; e++) {
      float v = acc8[e];
      if (v > v1) { v2 = v1; i2 = i1; v1 = v; i1 = e; }
      else if (v > v2) { v2 = v; i2 = e; }
    }
    float ex = expf(v2 - v1);
    float s = 1.0f + ex;
    tok_e[t * 2] = i1; tok_e[t * 2 + 1] = i2;
    tok_w[t * 2] = 1.0f / s; tok_w[t * 2 + 1] = ex / s;
    atomicAdd(&ctl[i1], 1);
    atomicAdd(&ctl[i2], 1);
  }
}

__global__ void scan_kernel(int* __restrict__ ctl) {
  if (threadIdx.x == 0 && blockIdx.x == 0) {
    int s = 0;
    for (int e = 0; e < NE; e++) {
      int c = ctl[e];
      ctl[16 + e] = s;
      ctl[8 + e] = s;
      s += c;
    }
  }
}

__global__ __launch_bounds__(256) void assign_kernel(
    const int* __restrict__ tok_e, const float* __restrict__ tok_w,
    int* __restrict__ ctl, int* __restrict__ tok_map, float* __restrict__ pair_w,
    int* __restrict__ islot) {
  int t = blockIdx.x * 256 + threadIdx.x;
  if (t < T_TOK) {
#pragma unroll
    for (int k = 0; k < 2; k++) {
      int e = tok_e[t * 2 + k];
      int slot = atomicAdd(&ctl[8 + e], 1);
      tok_map[slot] = t;
      pair_w[slot] = tok_w[t * 2 + k];
      islot[t * 2 + k] = slot;
    }
  }
}

// ---------------- combine: out[t] = sum_k w_k * (y[slot_k] + b2[e_k]) ----------
__global__ __launch_bounds__(256) void combine_kernel(
    const float* __restrict__ y, const float* __restrict__ b2,
    const int* __restrict__ tok_e, const int* __restrict__ islot,
    const float* __restrict__ tok_w, float* __restrict__ out) {
  int idx = blockIdx.x * 256 + threadIdx.x;
  int t = idx >> 8;
  int c4 = (idx & 255) * 4;
  int e0 = tok_e[t * 2], e1 = tok_e[t * 2 + 1];
  int s0 = islot[t * 2], s1 = islot[t * 2 + 1];
  float w0 = tok_w[t * 2], w1 = tok_w[t * 2 + 1];
  fl4 y0 = *(const fl4*)(y + (size_t)s0 * DM + c4);
  fl4 y1 = *(const fl4*)(y + (size_t)s1 * DM + c4);
  fl4 bb0 = *(const fl4*)(b2 + (size_t)e0 * DM + c4);
  fl4 bb1 = *(const fl4*)(b2 + (size_t)e1 * DM + c4);
  fl4 o;
#pragma unroll
  for (int i = 0; i < 4; i++) o[i] = w0 * (y0[i] + bb0[i]) + w1 * (y1[i] + bb1[i]);
  *(fl4*)(out + (size_t)t * DM + c4) = o;
}

// ---------------- grouped GEMM (m97-style 128x128 tile, BK=32, 4 waves) ------
// Proven structure from round 2 (411 TF here) with targeted fixes:
//  - XCD mt-fastest ordering (r4/r5: FETCH 327->64MB on 256-tiles)
//  - conflict-free LDS swizzle: chunk q holds global chunk q^((row>>2)&3)
//    (per-16-lane-pass: 2 lanes/16B-slot = free; old row&3 variant was 4-way)
//  - FC2 stores raw fp32 y rows (no bias/atomics); combine kernel finishes.
template <bool FC1>
__global__ __launch_bounds__(256) void moe_gemm(
    const u16* __restrict__ Abase, const u16* __restrict__ Wb,
    const float* __restrict__ bias, u16* __restrict__ Hout,
    float* __restrict__ Yout, const int* __restrict__ tok_map,
    const int* __restrict__ ctl) {
  constexpr int KTOT = FC1 ? DM : DH;
  constexpr int NTOT = FC1 ? DH : DM;
  constexpr int NT = NTOT / 128;
  constexpr int MT = 32;  // per-expert max 4096 rows / 128
  constexpr int NWG = NE * MT * NT;

  // XCD-aware: consecutive same-XCD swz sweep mt over one (e,nt) weight panel
  int bid = blockIdx.x;
  int swz = (bid & 7) * (NWG / 8) + (bid >> 3);
  int mt = swz % MT;
  int tmp = swz / MT;
  int nt = tmp % NT;
  int e = tmp / NT;

  int base = ctl[16 + e], cnt = ctl[e];
  if (mt * 128 >= cnt) return;

  __shared__ u16 As[128 * 32];
  __shared__ u16 Bs[128 * 32];

  int tid = threadIdx.x;
  int wv = tid >> 6, lane = tid & 63;
  int wr = wv >> 1, wc = wv & 1;
  int khalf = lane >> 4, l15 = lane & 15;

  // A staging (2 x 16B chunks/thread), swizzle pre-folded into global src
  const u16* asrc[2];
#pragma unroll
  for (int r2 = 0; r2 < 2; r2++) {
    int c = r2 * 256 + tid;
    int row = c >> 2, q = c & 3;
    int qs = q ^ ((row >> 2) & 3);
    int slot = base + mt * 128 + row;
    if (slot >= NSLOT) slot = NSLOT - 1;  // clamp; garbage rows masked on store
    size_t arow = FC1 ? (size_t)tok_map[slot] : (size_t)slot;
    asrc[r2] = Abase + arow * KTOT + qs * 8;
  }
  // B staging
  const u16* bsrc[2];
#pragma unroll
  for (int r2 = 0; r2 < 2; r2++) {
    int c = r2 * 256 + tid;
    int row = c >> 2, q = c & 3;
    int qs = q ^ ((row >> 2) & 3);
    bsrc[r2] = Wb + ((size_t)e * NTOT + nt * 128 + row) * KTOT + qs * 8;
  }

  // fragment LDS byte offsets (hoisted); read chunk = khalf ^ ((row>>2)&3)
  int aoff[4], boff[4];
#pragma unroll
  for (int m = 0; m < 4; m++) {
    int rowl = wr * 64 + m * 16 + l15;
    aoff[m] = rowl * 64 + ((khalf * 16) ^ ((rowl & 12) << 2));
  }
#pragma unroll
  for (int n = 0; n < 4; n++) {
    int coll = wc * 64 + n * 16 + l15;
    boff[n] = coll * 64 + ((khalf * 16) ^ ((coll & 12) << 2));
  }

  fl4 acc[4][4];
#pragma unroll
  for (int m = 0; m < 4; m++)
#pragma unroll
    for (int n = 0; n < 4; n++) acc[m][n] = (fl4){0.f, 0.f, 0.f, 0.f};

  for (int kt = 0; kt < KTOT / 32; ++kt) {
#pragma unroll
    for (int r2 = 0; r2 < 2; r2++)
      gload_lds16(asrc[r2] + kt * 32, &As[(r2 * 256 + wv * 64) * 8]);
#pragma unroll
    for (int r2 = 0; r2 < 2; r2++)
      gload_lds16(bsrc[r2] + kt * 32, &Bs[(r2 * 256 + wv * 64) * 8]);
    __syncthreads();

    sh8 af[4], bfr[4];
#pragma unroll
    for (int m = 0; m < 4; m++)
      af[m] = *(const sh8*)((const char*)As + aoff[m]);
#pragma unroll
    for (int n = 0; n < 4; n++)
      bfr[n] = *(const sh8*)((const char*)Bs + boff[n]);
#pragma unroll
    for (int m = 0; m < 4; m++)
#pragma unroll
      for (int n = 0; n < 4; n++)
        acc[m][n] = __builtin_amdgcn_mfma_f32_16x16x32_bf16(af[m], bfr[n], acc[m][n], 0, 0, 0);
    __syncthreads();
  }

  if (FC1) {
#pragma unroll
    for (int n = 0; n < 4; n++) {
      int colg = nt * 128 + wc * 64 + n * 16 + l15;
      float bn = bias[(size_t)e * DH + colg];
#pragma unroll
      for (int m = 0; m < 4; m++) {
#pragma unroll
        for (int j = 0; j < 4; j++) {
          int grow = mt * 128 + wr * 64 + m * 16 + khalf * 4 + j;
          if (grow < cnt) {
            float v = acc[m][n][j] + bn;
            Hout[(size_t)(base + grow) * DH + colg] = f2bf(gelu_tanh(v));
          }
        }
      }
    }
  } else {
#pragma unroll
    for (int m = 0; m < 4; m++) {
#pragma unroll
      for (int j = 0; j < 4; j++) {
        int grow = mt * 128 + wr * 64 + m * 16 + khalf * 4 + j;
        if (grow < cnt) {
          int slot = base + grow;
#pragma unroll
          for (int n = 0; n < 4; n++) {
            int colg = nt * 128 + wc * 64 + n * 16 + l15;
            Yout[(size_t)slot * DM + colg] = acc[m][n][j];
          }
        }
      }
    }
  }
}

extern "C" void kernel_launch(void* const* d_in, const int* in_sizes, int n_in,
                              void* d_out, int out_size, void* d_ws, size_t ws_size,
                              hipStream_t stream) {
  const float* x  = (const float*)d_in[0];
  const float* rw = (const float*)d_in[1];
  const float* w1 = (const float*)d_in[2];
  const float* b1 = (const float*)d_in[3];
  const float* w2 = (const float*)d_in[4];
  const float* b2 = (const float*)d_in[5];
  float* out = (float*)d_out;

  char* ws = (char*)d_ws;
  size_t off = 0;
  u16* xbf = (u16*)(ws + off); off += (size_t)T_TOK * DM * 2;
  u16* H   = (u16*)(ws + off); off += (size_t)NSLOT * DH * 2;
  u16* w1b = (u16*)(ws + off); off += WELEMS * 2;
  u16* w2b = (u16*)(ws + off); off += WELEMS * 2;
  int* tok_map  = (int*)(ws + off); off += (size_t)NSLOT * 4;
  float* pair_w = (float*)(ws + off); off += (size_t)NSLOT * 4;
  int* tok_e    = (int*)(ws + off); off += (size_t)T_TOK * 8;
  float* tok_w  = (float*)(ws + off); off += (size_t)T_TOK * 8;
  int* islot    = (int*)(ws + off); off += (size_t)T_TOK * 8;
  int* ctl      = (int*)(ws + off); off += 96;
  // y (fp32, 33.5 MB) overlays w1b (dead after fc1 GEMM)
  float* y = (float*)w1b;

  hipMemsetAsync(ctl, 0, 24 * 4, stream);

  router_kernel<<<T_TOK / 4, 256, 0, stream>>>(x, rw, xbf, tok_e, tok_w, ctl);
  scan_kernel<<<1, 64, 0, stream>>>(ctl);
  assign_kernel<<<T_TOK / 256, 256, 0, stream>>>(tok_e, tok_w, ctl, tok_map, pair_w, islot);
  wconv_kernel<<<8192, 256, 0, stream>>>(w1, w2, w1b, w2b);

  moe_gemm<true><<<NE * 32 * (DH / 128), 256, 0, stream>>>(
      xbf, w1b, b1, H, nullptr, tok_map, ctl);
  moe_gemm<false><<<NE * 32 * (DM / 128), 256, 0, stream>>>(
      H, w2b, nullptr, nullptr, y, tok_map, ctl);
  combine_kernel<<<T_TOK * DM / 4 / 256, 256, 0, stream>>>(
      y, b2, tok_e, islot, tok_w, out);
}

// Round 7
// 526.217 us; speedup vs baseline: 1.1161x; 1.1161x over previous
//
#include <hip/hip_runtime.h>
#include <hip/hip_bf16.h>

#define T_TOK 4096
#define DM 1024
#define DH 4096
#define NE 8
#define NSLOT (T_TOK * 2)
#define NSLOT_PAD (NSLOT + NE * 128)  // 9216: expert bases 128-aligned
#define MAXTILES 72                   // sum ceil(cnt_e/128) <= 64 + 8
#define WELEMS ((size_t)NE * DH * DM)

typedef __attribute__((ext_vector_type(4))) float fl4;
typedef __attribute__((ext_vector_type(8))) short sh8;
typedef __attribute__((ext_vector_type(8))) unsigned short us8;
typedef unsigned short u16;

__device__ __forceinline__ u16 f2bf(float f) {
  __hip_bfloat16 h = __float2bfloat16(f);
  return __builtin_bit_cast(u16, h);
}

__device__ __forceinline__ float gelu_tanh(float x) {
  float x3 = x * x * x;
  float u = 0.7978845608028654f * (x + 0.044715f * x3);
  return 0.5f * x * (1.0f + tanhf(u));
}

__device__ __forceinline__ void gload_lds16(const void* g, void* l) {
  __builtin_amdgcn_global_load_lds(
      (const __attribute__((address_space(1))) unsigned int*)g,
      (__attribute__((address_space(3))) unsigned int*)l, 16, 0, 0);
}

// ---------------- weight fp32 -> bf16 ----------------
__global__ __launch_bounds__(256) void wconv_kernel(
    const float* __restrict__ w1, const float* __restrict__ w2,
    u16* __restrict__ w1b, u16* __restrict__ w2b) {
  size_t stride = (size_t)gridDim.x * 256 * 8;
  for (size_t i = ((size_t)blockIdx.x * 256 + threadIdx.x) * 8; i < WELEMS; i += stride) {
    fl4 a0 = *(const fl4*)(w1 + i);
    fl4 a1 = *(const fl4*)(w1 + i + 4);
    fl4 b0 = *(const fl4*)(w2 + i);
    fl4 b1 = *(const fl4*)(w2 + i + 4);
    us8 oa, ob;
#pragma unroll
    for (int j = 0; j < 4; j++) {
      oa[j] = f2bf(a0[j]); oa[j + 4] = f2bf(a1[j]);
      ob[j] = f2bf(b0[j]); ob[j + 4] = f2bf(b1[j]);
    }
    *(us8*)(w1b + i) = oa;
    *(us8*)(w2b + i) = ob;
  }
}

// ---------------- router ----------------
__global__ __launch_bounds__(256) void router_kernel(
    const float* __restrict__ x, const float* __restrict__ rw,
    u16* __restrict__ xbf, int* __restrict__ tok_e, float* __restrict__ tok_w,
    int* __restrict__ ctl) {
  int tid = threadIdx.x;
  int wv = tid >> 6, lane = tid & 63;
  int t = blockIdx.x * 4 + wv;
  if (t >= T_TOK) return;

  const float* xp = x + (size_t)t * DM + lane * 16;
  fl4 xq[4];
#pragma unroll
  for (int i = 0; i < 4; i++) xq[i] = *(const fl4*)(xp + i * 4);

  float acc8[NE];
#pragma unroll
  for (int e = 0; e < NE; e++) {
    const float* wp = rw + (size_t)e * DM + lane * 16;
    float s = 0.f;
#pragma unroll
    for (int i = 0; i < 4; i++) {
      fl4 w4 = *(const fl4*)(wp + i * 4);
      s += xq[i][0] * w4[0] + xq[i][1] * w4[1] + xq[i][2] * w4[2] + xq[i][3] * w4[3];
    }
    acc8[e] = s;
  }
  us8 h0, h1;
#pragma unroll
  for (int i = 0; i < 8; i++) {
    h0[i] = f2bf(xq[i >> 2][i & 3]);
    h1[i] = f2bf(xq[2 + (i >> 2)][i & 3]);
  }
  *(us8*)(xbf + (size_t)t * DM + lane * 16) = h0;
  *(us8*)(xbf + (size_t)t * DM + lane * 16 + 8) = h1;

#pragma unroll
  for (int e = 0; e < NE; e++) {
#pragma unroll
    for (int off = 32; off > 0; off >>= 1) acc8[e] += __shfl_xor(acc8[e], off);
  }

  if (lane == 0) {
    float v1 = -1e30f, v2 = -1e30f;
    int i1 = 0, i2 = 0;
#pragma unroll
    for (int e = 0; e < NE; e++) {
      float v = acc8[e];
      if (v > v1) { v2 = v1; i2 = i1; v1 = v; i1 = e; }
      else if (v > v2) { v2 = v; i2 = e; }
    }
    float ex = expf(v2 - v1);
    float s = 1.0f + ex;
    tok_e[t * 2] = i1; tok_e[t * 2 + 1] = i2;
    tok_w[t * 2] = 1.0f / s; tok_w[t * 2 + 1] = ex / s;
    atomicAdd(&ctl[i1], 1);
    atomicAdd(&ctl[i2], 1);
  }
}

// ctl layout: [0..7] counts, [8..15] cursors, [16..23] padded bases,
// [31] ntiles, [32..103] tile_expert
__global__ void scan_kernel(int* __restrict__ ctl) {
  if (threadIdx.x == 0 && blockIdx.x == 0) {
    int s = 0, tb = 0;
    for (int e = 0; e < NE; e++) {
      int c = ctl[e];
      ctl[16 + e] = s;
      ctl[8 + e] = s;
      int nte = (c + 127) >> 7;
      for (int i = 0; i < nte; i++) ctl[32 + tb + i] = e;
      tb += nte;
      s += nte << 7;  // 128-aligned advance
    }
    ctl[31] = tb;
    for (; tb < MAXTILES; tb++) ctl[32 + tb] = -1;
  }
}

__global__ __launch_bounds__(256) void assign_kernel(
    const int* __restrict__ tok_e, const float* __restrict__ tok_w,
    int* __restrict__ ctl, int* __restrict__ tok_map, float* __restrict__ pair_w,
    int* __restrict__ islot) {
  int t = blockIdx.x * 256 + threadIdx.x;
  if (t < T_TOK) {
#pragma unroll
    for (int k = 0; k < 2; k++) {
      int e = tok_e[t * 2 + k];
      int slot = atomicAdd(&ctl[8 + e], 1);
      tok_map[slot] = t;
      pair_w[slot] = tok_w[t * 2 + k];
      islot[t * 2 + k] = slot;
    }
  }
}

// ---------------- combine: out[t] = sum_k w_k * (y[slot_k] + b2[e_k]) ----------
__global__ __launch_bounds__(256) void combine_kernel(
    const float* __restrict__ y, const float* __restrict__ b2,
    const int* __restrict__ tok_e, const int* __restrict__ islot,
    const float* __restrict__ tok_w, float* __restrict__ out) {
  int idx = blockIdx.x * 256 + threadIdx.x;
  int t = idx >> 8;
  int c4 = (idx & 255) * 4;
  int e0 = tok_e[t * 2], e1 = tok_e[t * 2 + 1];
  int s0 = islot[t * 2], s1 = islot[t * 2 + 1];
  float w0 = tok_w[t * 2], w1 = tok_w[t * 2 + 1];
  fl4 y0 = *(const fl4*)(y + (size_t)s0 * DM + c4);
  fl4 y1 = *(const fl4*)(y + (size_t)s1 * DM + c4);
  fl4 bb0 = *(const fl4*)(b2 + (size_t)e0 * DM + c4);
  fl4 bb1 = *(const fl4*)(b2 + (size_t)e1 * DM + c4);
  fl4 o;
#pragma unroll
  for (int i = 0; i < 4; i++) o[i] = w0 * (y0[i] + bb0[i]) + w1 * (y1[i] + bb1[i]);
  *(fl4*)(out + (size_t)t * DM + c4) = o;
}

// ------ grouped GEMM: 128x128 tile, BK=32, 4 waves, 2-phase double-buffer ----
// T3-minimum pipeline: stage(t+1 -> buf^1) issued BEFORE compute(t -> buf);
// one __syncthreads per K-step drains the stage issued a full compute earlier.
// Exact grid: tile index over 128-aligned expert bases (<=72 tiles).
template <bool FC1>
__global__ __launch_bounds__(256, 3) void moe_gemm(
    const u16* __restrict__ Abase, const u16* __restrict__ Wb,
    const float* __restrict__ bias, u16* __restrict__ Hout,
    float* __restrict__ Yout, const int* __restrict__ tok_map,
    const int* __restrict__ ctl) {
  constexpr int KTOT = FC1 ? DM : DH;
  constexpr int NTOT = FC1 ? DH : DM;
  constexpr int NT = NTOT / 128;
  constexpr int NK = KTOT / 32;
  constexpr int NWG = MAXTILES * NT;

  // XCD-aware: tile fastest within each XCD chunk (NWG % 8 == 0)
  int bid = blockIdx.x;
  int swz = (bid & 7) * (NWG / 8) + (bid >> 3);
  int tile = swz % MAXTILES;
  int nt = swz / MAXTILES;

  int e = ctl[32 + tile];
  if (e < 0) return;
  int cnt = ctl[e], base = ctl[16 + e];
  int rowlim = base + cnt;   // absolute valid-slot limit for this expert
  int m0 = tile * 128;       // absolute slot of tile row 0 (bases 128-aligned)

  __shared__ u16 As[2][128 * 32];
  __shared__ u16 Bs[2][128 * 32];

  int tid = threadIdx.x;
  int wv = tid >> 6, lane = tid & 63;
  int wr = wv >> 1, wc = wv & 1;
  int khalf = lane >> 4, l15 = lane & 15;

  // staging source ptrs (swizzle pre-folded: chunk q holds global q^((row>>2)&3))
  const u16* asrc[2];
  const u16* bsrc[2];
#pragma unroll
  for (int r2 = 0; r2 < 2; r2++) {
    int c = r2 * 256 + tid;
    int row = c >> 2, q = c & 3;
    int qs = q ^ ((row >> 2) & 3);
    int slot = m0 + row;
    size_t arow;
    if (FC1)
      arow = (slot < rowlim) ? (size_t)tok_map[slot] : 0;
    else
      arow = (size_t)slot;  // H sized NSLOT_PAD rows; garbage rows masked on store
    asrc[r2] = Abase + arow * KTOT + qs * 8;
    bsrc[r2] = Wb + ((size_t)e * NTOT + nt * 128 + row) * KTOT + qs * 8;
  }

#define STAGE(B, KT)                                                         \
  { _Pragma("unroll") for (int r2 = 0; r2 < 2; r2++) {                       \
      gload_lds16(asrc[r2] + (KT) * 32, &As[B][(r2 * 256 + wv * 64) * 8]);   \
      gload_lds16(bsrc[r2] + (KT) * 32, &Bs[B][(r2 * 256 + wv * 64) * 8]);   \
    } }

  // fragment LDS byte offsets (within one 8KB buffer)
  int aoff[4], boff[4];
#pragma unroll
  for (int m = 0; m < 4; m++) {
    int rowl = wr * 64 + m * 16 + l15;
    aoff[m] = rowl * 64 + ((khalf * 16) ^ ((rowl & 12) << 2));
  }
#pragma unroll
  for (int n = 0; n < 4; n++) {
    int coll = wc * 64 + n * 16 + l15;
    boff[n] = coll * 64 + ((khalf * 16) ^ ((coll & 12) << 2));
  }

  fl4 acc[4][4];
#pragma unroll
  for (int m = 0; m < 4; m++)
#pragma unroll
    for (int n = 0; n < 4; n++) acc[m][n] = (fl4){0.f, 0.f, 0.f, 0.f};

#define COMPUTE(B)                                                           \
  {                                                                          \
    sh8 af[4], bfr[4];                                                       \
    _Pragma("unroll") for (int m = 0; m < 4; m++)                            \
      af[m] = *(const sh8*)((const char*)As[B] + aoff[m]);                   \
    _Pragma("unroll") for (int n = 0; n < 4; n++)                            \
      bfr[n] = *(const sh8*)((const char*)Bs[B] + boff[n]);                  \
    _Pragma("unroll") for (int m = 0; m < 4; m++)                            \
    _Pragma("unroll") for (int n = 0; n < 4; n++)                            \
      acc[m][n] = __builtin_amdgcn_mfma_f32_16x16x32_bf16(af[m], bfr[n],     \
                                                          acc[m][n], 0, 0, 0); \
  }

  STAGE(0, 0);
  __syncthreads();
  for (int kt = 0; kt < NK; kt += 2) {
    STAGE(1, kt + 1);          // prefetch next while computing current
    COMPUTE(0);
    __syncthreads();           // drains this wave's stage; readers of buf0 done
    if (kt + 2 < NK) STAGE(0, kt + 2);
    COMPUTE(1);
    __syncthreads();
  }

  if (FC1) {
#pragma unroll
    for (int n = 0; n < 4; n++) {
      int colg = nt * 128 + wc * 64 + n * 16 + l15;
      float bn = bias[(size_t)e * DH + colg];
#pragma unroll
      for (int m = 0; m < 4; m++) {
#pragma unroll
        for (int j = 0; j < 4; j++) {
          int slot = m0 + wr * 64 + m * 16 + khalf * 4 + j;
          if (slot < rowlim) {
            float v = acc[m][n][j] + bn;
            Hout[(size_t)slot * DH + colg] = f2bf(gelu_tanh(v));
          }
        }
      }
    }
  } else {
#pragma unroll
    for (int m = 0; m < 4; m++) {
#pragma unroll
      for (int j = 0; j < 4; j++) {
        int slot = m0 + wr * 64 + m * 16 + khalf * 4 + j;
        if (slot < rowlim) {
#pragma unroll
          for (int n = 0; n < 4; n++) {
            int colg = nt * 128 + wc * 64 + n * 16 + l15;
            Yout[(size_t)slot * DM + colg] = acc[m][n][j];
          }
        }
      }
    }
  }
#undef STAGE
#undef COMPUTE
}

extern "C" void kernel_launch(void* const* d_in, const int* in_sizes, int n_in,
                              void* d_out, int out_size, void* d_ws, size_t ws_size,
                              hipStream_t stream) {
  const float* x  = (const float*)d_in[0];
  const float* rw = (const float*)d_in[1];
  const float* w1 = (const float*)d_in[2];
  const float* b1 = (const float*)d_in[3];
  const float* w2 = (const float*)d_in[4];
  const float* b2 = (const float*)d_in[5];
  float* out = (float*)d_out;

  char* ws = (char*)d_ws;
  size_t off = 0;
  u16* xbf = (u16*)(ws + off); off += (size_t)T_TOK * DM * 2;
  u16* H   = (u16*)(ws + off); off += (size_t)NSLOT_PAD * DH * 2;
  u16* w1b = (u16*)(ws + off); off += WELEMS * 2;
  u16* w2b = (u16*)(ws + off); off += WELEMS * 2;
  int* tok_map  = (int*)(ws + off); off += (size_t)NSLOT_PAD * 4;
  float* pair_w = (float*)(ws + off); off += (size_t)NSLOT_PAD * 4;
  int* tok_e    = (int*)(ws + off); off += (size_t)T_TOK * 8;
  float* tok_w  = (float*)(ws + off); off += (size_t)T_TOK * 8;
  int* islot    = (int*)(ws + off); off += (size_t)T_TOK * 8;
  int* ctl      = (int*)(ws + off); off += 512;
  // y (fp32, 37.7 MB) overlays w1b (67 MB, dead after fc1 GEMM)
  float* y = (float*)w1b;

  hipMemsetAsync(ctl, 0, 128 * 4, stream);

  router_kernel<<<T_TOK / 4, 256, 0, stream>>>(x, rw, xbf, tok_e, tok_w, ctl);
  scan_kernel<<<1, 64, 0, stream>>>(ctl);
  assign_kernel<<<T_TOK / 256, 256, 0, stream>>>(tok_e, tok_w, ctl, tok_map, pair_w, islot);
  wconv_kernel<<<8192, 256, 0, stream>>>(w1, w2, w1b, w2b);

  moe_gemm<true><<<MAXTILES * (DH / 128), 256, 0, stream>>>(
      xbf, w1b, b1, H, nullptr, tok_map, ctl);
  moe_gemm<false><<<MAXTILES * (DM / 128), 256, 0, stream>>>(
      H, w2b, nullptr, nullptr, y, tok_map, ctl);
  combine_kernel<<<T_TOK * DM / 4 / 256, 256, 0, stream>>>(
      y, b2, tok_e, islot, tok_w, out);
}

// Round 8
// 503.710 us; speedup vs baseline: 1.1659x; 1.0447x over previous
//
#include <hip/hip_runtime.h>
#include <hip/hip_bf16.h>

#define T_TOK 4096
#define DM 1024
#define DH 4096
#define NE 8
#define NSLOT (T_TOK * 2)
#define NSLOT_PAD (NSLOT + NE * 128)  // 9216: expert bases 128-aligned
#define MAXTILES 72                   // sum ceil(cnt_e/128) <= 64 + 8
#define WELEMS ((size_t)NE * DH * DM)

typedef __attribute__((ext_vector_type(4))) float fl4;
typedef __attribute__((ext_vector_type(8))) short sh8;
typedef __attribute__((ext_vector_type(8))) unsigned short us8;
typedef unsigned short u16;

__device__ __forceinline__ u16 f2bf(float f) {
  __hip_bfloat16 h = __float2bfloat16(f);
  return __builtin_bit_cast(u16, h);
}

__device__ __forceinline__ float gelu_tanh(float x) {
  float x3 = x * x * x;
  float u = 0.7978845608028654f * (x + 0.044715f * x3);
  return 0.5f * x * (1.0f + tanhf(u));
}

__device__ __forceinline__ void gload_lds16(const void* g, void* l) {
  __builtin_amdgcn_global_load_lds(
      (const __attribute__((address_space(1))) unsigned int*)g,
      (__attribute__((address_space(3))) unsigned int*)l, 16, 0, 0);
}

// ---------------- weight fp32 -> bf16 ----------------
__global__ __launch_bounds__(256) void wconv_kernel(
    const float* __restrict__ w1, const float* __restrict__ w2,
    u16* __restrict__ w1b, u16* __restrict__ w2b) {
  size_t stride = (size_t)gridDim.x * 256 * 8;
  for (size_t i = ((size_t)blockIdx.x * 256 + threadIdx.x) * 8; i < WELEMS; i += stride) {
    fl4 a0 = *(const fl4*)(w1 + i);
    fl4 a1 = *(const fl4*)(w1 + i + 4);
    fl4 b0 = *(const fl4*)(w2 + i);
    fl4 b1 = *(const fl4*)(w2 + i + 4);
    us8 oa, ob;
#pragma unroll
    for (int j = 0; j < 4; j++) {
      oa[j] = f2bf(a0[j]); oa[j + 4] = f2bf(a1[j]);
      ob[j] = f2bf(b0[j]); ob[j + 4] = f2bf(b1[j]);
    }
    *(us8*)(w1b + i) = oa;
    *(us8*)(w2b + i) = ob;
  }
}

// ---------------- router ----------------
__global__ __launch_bounds__(256) void router_kernel(
    const float* __restrict__ x, const float* __restrict__ rw,
    u16* __restrict__ xbf, int* __restrict__ tok_e, float* __restrict__ tok_w,
    int* __restrict__ ctl) {
  int tid = threadIdx.x;
  int wv = tid >> 6, lane = tid & 63;
  int t = blockIdx.x * 4 + wv;
  if (t >= T_TOK) return;

  const float* xp = x + (size_t)t * DM + lane * 16;
  fl4 xq[4];
#pragma unroll
  for (int i = 0; i < 4; i++) xq[i] = *(const fl4*)(xp + i * 4);

  float acc8[NE];
#pragma unroll
  for (int e = 0; e < NE; e++) {
    const float* wp = rw + (size_t)e * DM + lane * 16;
    float s = 0.f;
#pragma unroll
    for (int i = 0; i < 4; i++) {
      fl4 w4 = *(const fl4*)(wp + i * 4);
      s += xq[i][0] * w4[0] + xq[i][1] * w4[1] + xq[i][2] * w4[2] + xq[i][3] * w4[3];
    }
    acc8[e] = s;
  }
  us8 h0, h1;
#pragma unroll
  for (int i = 0; i < 8; i++) {
    h0[i] = f2bf(xq[i >> 2][i & 3]);
    h1[i] = f2bf(xq[2 + (i >> 2)][i & 3]);
  }
  *(us8*)(xbf + (size_t)t * DM + lane * 16) = h0;
  *(us8*)(xbf + (size_t)t * DM + lane * 16 + 8) = h1;

#pragma unroll
  for (int e = 0; e < NE; e++) {
#pragma unroll
    for (int off = 32; off > 0; off >>= 1) acc8[e] += __shfl_xor(acc8[e], off);
  }

  if (lane == 0) {
    float v1 = -1e30f, v2 = -1e30f;
    int i1 = 0, i2 = 0;
#pragma unroll
    for (int e = 0; e < NE; e++) {
      float v = acc8[e];
      if (v > v1) { v2 = v1; i2 = i1; v1 = v; i1 = e; }
      else if (v > v2) { v2 = v; i2 = e; }
    }
    float ex = expf(v2 - v1);
    float s = 1.0f + ex;
    tok_e[t * 2] = i1; tok_e[t * 2 + 1] = i2;
    tok_w[t * 2] = 1.0f / s; tok_w[t * 2 + 1] = ex / s;
    atomicAdd(&ctl[i1], 1);
    atomicAdd(&ctl[i2], 1);
  }
}

// ctl layout: [0..7] counts, [8..15] cursors, [16..23] padded bases,
// [31] ntiles, [32..103] tile_expert
// Parallel scan: per-thread global ops, only an 8-iter LDS loop serial.
__global__ __launch_bounds__(128) void scan_kernel(int* __restrict__ ctl) {
  __shared__ int cnt_s[NE];
  __shared__ int base_s[NE];
  __shared__ int tb_s[NE + 1];
  int tid = threadIdx.x;
  if (tid < NE) cnt_s[tid] = ctl[tid];
  __syncthreads();
  if (tid == 0) {
    int s = 0, tb = 0;
    for (int e = 0; e < NE; e++) {
      base_s[e] = s;
      tb_s[e] = tb;
      int nte = (cnt_s[e] + 127) >> 7;
      tb += nte;
      s += nte << 7;
    }
    tb_s[NE] = tb;
  }
  __syncthreads();
  if (tid < NE) { ctl[16 + tid] = base_s[tid]; ctl[8 + tid] = base_s[tid]; }
  if (tid == 0) ctl[31] = tb_s[NE];
  if (tid < MAXTILES) {
    int e = -1;
#pragma unroll
    for (int k = 0; k < NE; k++)
      if (tid >= tb_s[k] && tid < tb_s[k + 1]) e = k;
    ctl[32 + tid] = e;
  }
}

__global__ __launch_bounds__(256) void assign_kernel(
    const int* __restrict__ tok_e, const float* __restrict__ tok_w,
    int* __restrict__ ctl, int* __restrict__ tok_map, float* __restrict__ pair_w,
    int* __restrict__ islot) {
  int t = blockIdx.x * 256 + threadIdx.x;
  if (t < T_TOK) {
#pragma unroll
    for (int k = 0; k < 2; k++) {
      int e = tok_e[t * 2 + k];
      int slot = atomicAdd(&ctl[8 + e], 1);
      tok_map[slot] = t;
      pair_w[slot] = tok_w[t * 2 + k];
      islot[t * 2 + k] = slot;
    }
  }
}

// ---------------- combine: out[t] = sum_k w_k * (y[slot_k] + b2[e_k]) ----------
__global__ __launch_bounds__(256) void combine_kernel(
    const float* __restrict__ y, const float* __restrict__ b2,
    const int* __restrict__ tok_e, const int* __restrict__ islot,
    const float* __restrict__ tok_w, float* __restrict__ out) {
  int idx = blockIdx.x * 256 + threadIdx.x;
  int t = idx >> 8;
  int c4 = (idx & 255) * 4;
  int e0 = tok_e[t * 2], e1 = tok_e[t * 2 + 1];
  int s0 = islot[t * 2], s1 = islot[t * 2 + 1];
  float w0 = tok_w[t * 2], w1 = tok_w[t * 2 + 1];
  fl4 y0 = *(const fl4*)(y + (size_t)s0 * DM + c4);
  fl4 y1 = *(const fl4*)(y + (size_t)s1 * DM + c4);
  fl4 bb0 = *(const fl4*)(b2 + (size_t)e0 * DM + c4);
  fl4 bb1 = *(const fl4*)(b2 + (size_t)e1 * DM + c4);
  fl4 o;
#pragma unroll
  for (int i = 0; i < 4; i++) o[i] = w0 * (y0[i] + bb0[i]) + w1 * (y1[i] + bb1[i]);
  *(fl4*)(out + (size_t)t * DM + c4) = o;
}

// ------ grouped GEMM: 128x128 tile, BK=32, 4 waves, dbuf + COUNTED vmcnt ------
// T4 applied to the 2-phase loop: raw s_barrier (no implicit vmcnt-0 drain);
// each iter waits vmcnt(4) = the stage issued ONE FULL K-step earlier.
// Race-safety: 2 raw barriers per K-step -> STAGE(buf) at iter k+1 is
// separated from iter k's COMPUTE(buf) reads by the post-compute barrier;
// cross-wave stage visibility = own-wave vmcnt(4) before pre-compute barrier.
template <bool FC1>
__global__ __launch_bounds__(256, 4) void moe_gemm(
    const u16* __restrict__ Abase, const u16* __restrict__ Wb,
    const float* __restrict__ bias, u16* __restrict__ Hout,
    float* __restrict__ Yout, const int* __restrict__ tok_map,
    const int* __restrict__ ctl) {
  constexpr int KTOT = FC1 ? DM : DH;
  constexpr int NTOT = FC1 ? DH : DM;
  constexpr int NT = NTOT / 128;
  constexpr int NK = KTOT / 32;
  constexpr int NWG = MAXTILES * NT;

  // XCD-aware: tile fastest within each XCD chunk (NWG % 8 == 0)
  int bid = blockIdx.x;
  int swz = (bid & 7) * (NWG / 8) + (bid >> 3);
  int tile = swz % MAXTILES;
  int nt = swz / MAXTILES;

  int e = ctl[32 + tile];
  if (e < 0) return;
  int cnt = ctl[e], base = ctl[16 + e];
  int rowlim = base + cnt;
  int m0 = tile * 128;

  __shared__ u16 As[2][128 * 32];
  __shared__ u16 Bs[2][128 * 32];

  int tid = threadIdx.x;
  int wv = tid >> 6, lane = tid & 63;
  int wr = wv >> 1, wc = wv & 1;
  int khalf = lane >> 4, l15 = lane & 15;

  const u16* asrc[2];
  const u16* bsrc[2];
#pragma unroll
  for (int r2 = 0; r2 < 2; r2++) {
    int c = r2 * 256 + tid;
    int row = c >> 2, q = c & 3;
    int qs = q ^ ((row >> 2) & 3);
    int slot = m0 + row;
    size_t arow;
    if (FC1)
      arow = (slot < rowlim) ? (size_t)tok_map[slot] : 0;
    else
      arow = (size_t)slot;
    asrc[r2] = Abase + arow * KTOT + qs * 8;
    bsrc[r2] = Wb + ((size_t)e * NTOT + nt * 128 + row) * KTOT + qs * 8;
  }

#define STAGE(B, KT)                                                         \
  { _Pragma("unroll") for (int r2 = 0; r2 < 2; r2++) {                       \
      gload_lds16(asrc[r2] + (KT) * 32, &As[B][(r2 * 256 + wv * 64) * 8]);   \
      gload_lds16(bsrc[r2] + (KT) * 32, &Bs[B][(r2 * 256 + wv * 64) * 8]);   \
    } }

  int aoff[4], boff[4];
#pragma unroll
  for (int m = 0; m < 4; m++) {
    int rowl = wr * 64 + m * 16 + l15;
    aoff[m] = rowl * 64 + ((khalf * 16) ^ ((rowl & 12) << 2));
  }
#pragma unroll
  for (int n = 0; n < 4; n++) {
    int coll = wc * 64 + n * 16 + l15;
    boff[n] = coll * 64 + ((khalf * 16) ^ ((coll & 12) << 2));
  }

  fl4 acc[4][4];
#pragma unroll
  for (int m = 0; m < 4; m++)
#pragma unroll
    for (int n = 0; n < 4; n++) acc[m][n] = (fl4){0.f, 0.f, 0.f, 0.f};

#define COMPUTE(B)                                                           \
  {                                                                          \
    sh8 af[4], bfr[4];                                                       \
    _Pragma("unroll") for (int m = 0; m < 4; m++)                            \
      af[m] = *(const sh8*)((const char*)As[B] + aoff[m]);                   \
    _Pragma("unroll") for (int n = 0; n < 4; n++)                            \
      bfr[n] = *(const sh8*)((const char*)Bs[B] + boff[n]);                  \
    __builtin_amdgcn_s_setprio(1);                                           \
    _Pragma("unroll") for (int m = 0; m < 4; m++)                            \
    _Pragma("unroll") for (int n = 0; n < 4; n++)                            \
      acc[m][n] = __builtin_amdgcn_mfma_f32_16x16x32_bf16(af[m], bfr[n],     \
                                                          acc[m][n], 0, 0, 0); \
    __builtin_amdgcn_s_setprio(0);                                           \
  }

  STAGE(0, 0);
  for (int kt = 0; kt < NK; kt += 2) {
    // K-step kt: compute buf0 (staged one step ago), stage buf1 <- kt+1
    STAGE(1, kt + 1);
    asm volatile("s_waitcnt vmcnt(4)" ::: "memory");  // drain prior stage only
    __builtin_amdgcn_s_barrier();
    COMPUTE(0);
    __builtin_amdgcn_s_barrier();  // buf0 readers done before its next overwrite
    // K-step kt+1: compute buf1, stage buf0 <- kt+2
    if (kt + 2 < NK) {
      STAGE(0, kt + 2);
      asm volatile("s_waitcnt vmcnt(4)" ::: "memory");
    } else {
      asm volatile("s_waitcnt vmcnt(0)" ::: "memory");
    }
    __builtin_amdgcn_s_barrier();
    COMPUTE(1);
    __builtin_amdgcn_s_barrier();
  }

  if (FC1) {
#pragma unroll
    for (int n = 0; n < 4; n++) {
      int colg = nt * 128 + wc * 64 + n * 16 + l15;
      float bn = bias[(size_t)e * DH + colg];
#pragma unroll
      for (int m = 0; m < 4; m++) {
#pragma unroll
        for (int j = 0; j < 4; j++) {
          int slot = m0 + wr * 64 + m * 16 + khalf * 4 + j;
          if (slot < rowlim) {
            float v = acc[m][n][j] + bn;
            Hout[(size_t)slot * DH + colg] = f2bf(gelu_tanh(v));
          }
        }
      }
    }
  } else {
#pragma unroll
    for (int m = 0; m < 4; m++) {
#pragma unroll
      for (int j = 0; j < 4; j++) {
        int slot = m0 + wr * 64 + m * 16 + khalf * 4 + j;
        if (slot < rowlim) {
#pragma unroll
          for (int n = 0; n < 4; n++) {
            int colg = nt * 128 + wc * 64 + n * 16 + l15;
            Yout[(size_t)slot * DM + colg] = acc[m][n][j];
          }
        }
      }
    }
  }
#undef STAGE
#undef COMPUTE
}

extern "C" void kernel_launch(void* const* d_in, const int* in_sizes, int n_in,
                              void* d_out, int out_size, void* d_ws, size_t ws_size,
                              hipStream_t stream) {
  const float* x  = (const float*)d_in[0];
  const float* rw = (const float*)d_in[1];
  const float* w1 = (const float*)d_in[2];
  const float* b1 = (const float*)d_in[3];
  const float* w2 = (const float*)d_in[4];
  const float* b2 = (const float*)d_in[5];
  float* out = (float*)d_out;

  char* ws = (char*)d_ws;
  size_t off = 0;
  u16* xbf = (u16*)(ws + off); off += (size_t)T_TOK * DM * 2;
  u16* H   = (u16*)(ws + off); off += (size_t)NSLOT_PAD * DH * 2;
  u16* w1b = (u16*)(ws + off); off += WELEMS * 2;
  u16* w2b = (u16*)(ws + off); off += WELEMS * 2;
  int* tok_map  = (int*)(ws + off); off += (size_t)NSLOT_PAD * 4;
  float* pair_w = (float*)(ws + off); off += (size_t)NSLOT_PAD * 4;
  int* tok_e    = (int*)(ws + off); off += (size_t)T_TOK * 8;
  float* tok_w  = (float*)(ws + off); off += (size_t)T_TOK * 8;
  int* islot    = (int*)(ws + off); off += (size_t)T_TOK * 8;
  int* ctl      = (int*)(ws + off); off += 512;
  // y (fp32, 37.7 MB) overlays w1b (67 MB, dead after fc1 GEMM)
  float* y = (float*)w1b;

  hipMemsetAsync(ctl, 0, 128 * 4, stream);

  router_kernel<<<T_TOK / 4, 256, 0, stream>>>(x, rw, xbf, tok_e, tok_w, ctl);
  scan_kernel<<<1, 128, 0, stream>>>(ctl);
  assign_kernel<<<T_TOK / 256, 256, 0, stream>>>(tok_e, tok_w, ctl, tok_map, pair_w, islot);
  wconv_kernel<<<8192, 256, 0, stream>>>(w1, w2, w1b, w2b);

  moe_gemm<true><<<MAXTILES * (DH / 128), 256, 0, stream>>>(
      xbf, w1b, b1, H, nullptr, tok_map, ctl);
  moe_gemm<false><<<MAXTILES * (DM / 128), 256, 0, stream>>>(
      H, w2b, nullptr, nullptr, y, tok_map, ctl);
  combine_kernel<<<T_TOK * DM / 4 / 256, 256, 0, stream>>>(
      y, b2, tok_e, islot, tok_w, out);
}

// Round 9
// 478.700 us; speedup vs baseline: 1.2268x; 1.0522x over previous
//
#include <hip/hip_runtime.h>
#include <hip/hip_bf16.h>

#define T_TOK 4096
#define DM 1024
#define DH 4096
#define NE 8
#define NSLOT (T_TOK * 2)
#define NSLOT_PAD (NSLOT + NE * 128)  // 9216: expert bases 128-aligned
#define MAXTILES 72                   // 8 XCDs x 9 tiles
#define WELEMS ((size_t)NE * DH * DM)

typedef __attribute__((ext_vector_type(4))) float fl4;
typedef __attribute__((ext_vector_type(8))) short sh8;
typedef __attribute__((ext_vector_type(8))) unsigned short us8;
typedef unsigned short u16;

__device__ __forceinline__ u16 f2bf(float f) {
  __hip_bfloat16 h = __float2bfloat16(f);
  return __builtin_bit_cast(u16, h);
}

__device__ __forceinline__ float gelu_tanh(float x) {
  float x3 = x * x * x;
  float u = 0.7978845608028654f * (x + 0.044715f * x3);
  return 0.5f * x * (1.0f + tanhf(u));
}

__device__ __forceinline__ void gload_lds16(const void* g, void* l) {
  __builtin_amdgcn_global_load_lds(
      (const __attribute__((address_space(1))) unsigned int*)g,
      (__attribute__((address_space(3))) unsigned int*)l, 16, 0, 0);
}

// ---------------- weight fp32 -> bf16 ----------------
__global__ __launch_bounds__(256) void wconv_kernel(
    const float* __restrict__ w1, const float* __restrict__ w2,
    u16* __restrict__ w1b, u16* __restrict__ w2b) {
  size_t stride = (size_t)gridDim.x * 256 * 8;
  for (size_t i = ((size_t)blockIdx.x * 256 + threadIdx.x) * 8; i < WELEMS; i += stride) {
    fl4 a0 = *(const fl4*)(w1 + i);
    fl4 a1 = *(const fl4*)(w1 + i + 4);
    fl4 b0 = *(const fl4*)(w2 + i);
    fl4 b1 = *(const fl4*)(w2 + i + 4);
    us8 oa, ob;
#pragma unroll
    for (int j = 0; j < 4; j++) {
      oa[j] = f2bf(a0[j]); oa[j + 4] = f2bf(a1[j]);
      ob[j] = f2bf(b0[j]); ob[j + 4] = f2bf(b1[j]);
    }
    *(us8*)(w1b + i) = oa;
    *(us8*)(w2b + i) = ob;
  }
}

// ---------------- router ----------------
__global__ __launch_bounds__(256) void router_kernel(
    const float* __restrict__ x, const float* __restrict__ rw,
    u16* __restrict__ xbf, int* __restrict__ tok_e, float* __restrict__ tok_w,
    int* __restrict__ ctl) {
  int tid = threadIdx.x;
  int wv = tid >> 6, lane = tid & 63;
  int t = blockIdx.x * 4 + wv;
  if (t >= T_TOK) return;

  const float* xp = x + (size_t)t * DM + lane * 16;
  fl4 xq[4];
#pragma unroll
  for (int i = 0; i < 4; i++) xq[i] = *(const fl4*)(xp + i * 4);

  float acc8[NE];
#pragma unroll
  for (int e = 0; e < NE; e++) {
    const float* wp = rw + (size_t)e * DM + lane * 16;
    float s = 0.f;
#pragma unroll
    for (int i = 0; i < 4; i++) {
      fl4 w4 = *(const fl4*)(wp + i * 4);
      s += xq[i][0] * w4[0] + xq[i][1] * w4[1] + xq[i][2] * w4[2] + xq[i][3] * w4[3];
    }
    acc8[e] = s;
  }
  us8 h0, h1;
#pragma unroll
  for (int i = 0; i < 8; i++) {
    h0[i] = f2bf(xq[i >> 2][i & 3]);
    h1[i] = f2bf(xq[2 + (i >> 2)][i & 3]);
  }
  *(us8*)(xbf + (size_t)t * DM + lane * 16) = h0;
  *(us8*)(xbf + (size_t)t * DM + lane * 16 + 8) = h1;

#pragma unroll
  for (int e = 0; e < NE; e++) {
#pragma unroll
    for (int off = 32; off > 0; off >>= 1) acc8[e] += __shfl_xor(acc8[e], off);
  }

  if (lane == 0) {
    float v1 = -1e30f, v2 = -1e30f;
    int i1 = 0, i2 = 0;
#pragma unroll
    for (int e = 0; e < NE; e++) {
      float v = acc8[e];
      if (v > v1) { v2 = v1; i2 = i1; v1 = v; i1 = e; }
      else if (v > v2) { v2 = v; i2 = e; }
    }
    float ex = expf(v2 - v1);
    float s = 1.0f + ex;
    tok_e[t * 2] = i1; tok_e[t * 2 + 1] = i2;
    tok_w[t * 2] = 1.0f / s; tok_w[t * 2 + 1] = ex / s;
    atomicAdd(&ctl[i1], 1);
    atomicAdd(&ctl[i2], 1);
  }
}

// ctl layout: [0..7] counts, [8..15] cursors, [16..23] padded bases,
// [31] ntiles, [32..103] tile_expert
__global__ __launch_bounds__(128) void scan_kernel(int* __restrict__ ctl) {
  __shared__ int cnt_s[NE];
  __shared__ int tb_s[NE + 1];
  __shared__ int base_s[NE];
  int tid = threadIdx.x;
  if (tid < NE) cnt_s[tid] = ctl[tid];
  __syncthreads();
  if (tid == 0) {
    int s = 0, tb = 0;
    for (int e = 0; e < NE; e++) {
      base_s[e] = s;
      tb_s[e] = tb;
      int nte = (cnt_s[e] + 127) >> 7;
      tb += nte;
      s += nte << 7;
    }
    tb_s[NE] = tb;
  }
  __syncthreads();
  if (tid < NE) { ctl[16 + tid] = base_s[tid]; ctl[8 + tid] = base_s[tid]; }
  if (tid == 0) ctl[31] = tb_s[NE];
  if (tid < MAXTILES) {
    int e = -1;
#pragma unroll
    for (int k = 0; k < NE; k++)
      if (tid >= tb_s[k] && tid < tb_s[k + 1]) e = k;
    ctl[32 + tid] = e;
  }
}

__global__ __launch_bounds__(256) void assign_kernel(
    const int* __restrict__ tok_e, const float* __restrict__ tok_w,
    int* __restrict__ ctl, int* __restrict__ tok_map, float* __restrict__ pair_w,
    int* __restrict__ islot) {
  int t = blockIdx.x * 256 + threadIdx.x;
  if (t < T_TOK) {
#pragma unroll
    for (int k = 0; k < 2; k++) {
      int e = tok_e[t * 2 + k];
      int slot = atomicAdd(&ctl[8 + e], 1);
      tok_map[slot] = t;
      pair_w[slot] = tok_w[t * 2 + k];
      islot[t * 2 + k] = slot;
    }
  }
}

// ---------------- combine: out[t] = sum_k w_k * (y[slot_k] + b2[e_k]) ----------
__global__ __launch_bounds__(256) void combine_kernel(
    const float* __restrict__ y, const float* __restrict__ b2,
    const int* __restrict__ tok_e, const int* __restrict__ islot,
    const float* __restrict__ tok_w, float* __restrict__ out) {
  int idx = blockIdx.x * 256 + threadIdx.x;
  int t = idx >> 8;
  int c4 = (idx & 255) * 4;
  int e0 = tok_e[t * 2], e1 = tok_e[t * 2 + 1];
  int s0 = islot[t * 2], s1 = islot[t * 2 + 1];
  float w0 = tok_w[t * 2], w1 = tok_w[t * 2 + 1];
  fl4 y0 = *(const fl4*)(y + (size_t)s0 * DM + c4);
  fl4 y1 = *(const fl4*)(y + (size_t)s1 * DM + c4);
  fl4 bb0 = *(const fl4*)(b2 + (size_t)e0 * DM + c4);
  fl4 bb1 = *(const fl4*)(b2 + (size_t)e1 * DM + c4);
  fl4 o;
#pragma unroll
  for (int i = 0; i < 4; i++) o[i] = w0 * (y0[i] + bb0[i]) + w1 * (y1[i] + bb1[i]);
  *(fl4*)(out + (size_t)t * DM + c4) = o;
}

// ---- grouped GEMM: 128x128 tile, BK=32, 4 waves, 3-buffer distance-2 pipe ----
// Per K-step: vmcnt(4) [drains stage issued 2 K-steps ago] -> s_barrier ->
// sched_barrier(0) -> ds_reads(buf kt%3) -> STAGE(buf (kt+2)%3 <- kt+2) ->
// MFMA. ONE barrier per K-step.
// Race-safety: stage target b[(kt+2)%3] was last read at iter kt-1; every
// wave's iter kt-1 ds_reads are consumed (lgkmcnt before MFMA) before it
// reaches iter kt's barrier, and stages are issued after that barrier.
// Own-buffer validity: wave's own 4 loads drained by vmcnt(4) pre-barrier;
// other waves' chunks drained by their own vmcnt before their barrier.
// vmcnt uniformity: exactly one 4-load stage per iter (tail stages clamped,
// never skipped) -> outstanding is always 8 at the wait.
template <bool FC1>
__global__ __launch_bounds__(256, 3) void moe_gemm(
    const u16* __restrict__ Abase, const u16* __restrict__ Wb,
    const float* __restrict__ bias, u16* __restrict__ Hout,
    float* __restrict__ Yout, const int* __restrict__ tok_map,
    const int* __restrict__ ctl) {
  constexpr int KTOT = FC1 ? DM : DH;
  constexpr int NTOT = FC1 ? DH : DM;
  constexpr int NT = NTOT / 128;
  constexpr int NK = KTOT / 32;
  constexpr int NWG = MAXTILES * NT;
  constexpr int W = (NT < 8) ? NT : 8;

  // 2D XCD blocking: XCD x owns tiles [9x, 9x+9); inner order = 8-nt group x
  // tile so ~96 concurrent blocks/XCD touch A ~2.3MB + B ~2-4MB (fits L2).
  int bid = blockIdx.x;
  int x = bid & 7;
  int idx = bid >> 3;               // [0, NWG/8)
  int band = idx / (9 * W);
  int rem = idx - band * (9 * W);
  int tl = rem / W;
  int ntl = rem - tl * W;
  int nt = band * W + ntl;
  int tile = x * 9 + tl;

  int e = ctl[32 + tile];
  if (e < 0) return;
  int cnt = ctl[e], base = ctl[16 + e];
  int rowlim = base + cnt;
  int m0 = tile * 128;

  __shared__ u16 As[3][128 * 32];
  __shared__ u16 Bs[3][128 * 32];

  int tid = threadIdx.x;
  int wv = tid >> 6, lane = tid & 63;
  int wr = wv >> 1, wc = wv & 1;
  int khalf = lane >> 4, l15 = lane & 15;

  const u16* asrc[2];
  const u16* bsrc[2];
#pragma unroll
  for (int r2 = 0; r2 < 2; r2++) {
    int c = r2 * 256 + tid;
    int row = c >> 2, q = c & 3;
    int qs = q ^ ((row >> 2) & 3);
    int slot = m0 + row;
    size_t arow;
    if (FC1)
      arow = (slot < rowlim) ? (size_t)tok_map[slot] : 0;
    else
      arow = (size_t)slot;
    asrc[r2] = Abase + arow * KTOT + qs * 8;
    bsrc[r2] = Wb + ((size_t)e * NTOT + nt * 128 + row) * KTOT + qs * 8;
  }

#define STAGE(B, KT)                                                         \
  { _Pragma("unroll") for (int r2 = 0; r2 < 2; r2++) {                       \
      gload_lds16(asrc[r2] + (KT) * 32, &As[B][(r2 * 256 + wv * 64) * 8]);   \
      gload_lds16(bsrc[r2] + (KT) * 32, &Bs[B][(r2 * 256 + wv * 64) * 8]);   \
    } }

  int aoff[4], boff[4];
#pragma unroll
  for (int m = 0; m < 4; m++) {
    int rowl = wr * 64 + m * 16 + l15;
    aoff[m] = rowl * 64 + ((khalf * 16) ^ ((rowl & 12) << 2));
  }
#pragma unroll
  for (int n = 0; n < 4; n++) {
    int coll = wc * 64 + n * 16 + l15;
    boff[n] = coll * 64 + ((khalf * 16) ^ ((coll & 12) << 2));
  }

  fl4 acc[4][4];
#pragma unroll
  for (int m = 0; m < 4; m++)
#pragma unroll
    for (int n = 0; n < 4; n++) acc[m][n] = (fl4){0.f, 0.f, 0.f, 0.f};

#define ITER(B, KT)                                                          \
  if ((KT) < NK) {                                                           \
    asm volatile("s_waitcnt vmcnt(4)" ::: "memory");                         \
    __builtin_amdgcn_s_barrier();                                            \
    __builtin_amdgcn_sched_barrier(0);                                       \
    sh8 af[4], bfr[4];                                                       \
    _Pragma("unroll") for (int m = 0; m < 4; m++)                            \
      af[m] = *(const sh8*)((const char*)As[B] + aoff[m]);                   \
    _Pragma("unroll") for (int n = 0; n < 4; n++)                            \
      bfr[n] = *(const sh8*)((const char*)Bs[B] + boff[n]);                  \
    {                                                                        \
      int knext = ((KT) + 2 < NK) ? (KT) + 2 : NK - 1;                       \
      STAGE((B + 2) % 3, knext);                                             \
    }                                                                        \
    __builtin_amdgcn_s_setprio(1);                                           \
    _Pragma("unroll") for (int m = 0; m < 4; m++)                            \
    _Pragma("unroll") for (int n = 0; n < 4; n++)                            \
      acc[m][n] = __builtin_amdgcn_mfma_f32_16x16x32_bf16(af[m], bfr[n],     \
                                                          acc[m][n], 0, 0, 0); \
    __builtin_amdgcn_s_setprio(0);                                           \
  }

  STAGE(0, 0);
  STAGE(1, 1);
  for (int kt = 0; kt < NK; kt += 3) {
    ITER(0, kt);
    ITER(1, kt + 1);
    ITER(2, kt + 2);
  }
  asm volatile("s_waitcnt vmcnt(0)" ::: "memory");

  if (FC1) {
#pragma unroll
    for (int n = 0; n < 4; n++) {
      int colg = nt * 128 + wc * 64 + n * 16 + l15;
      float bn = bias[(size_t)e * DH + colg];
#pragma unroll
      for (int m = 0; m < 4; m++) {
#pragma unroll
        for (int j = 0; j < 4; j++) {
          int slot = m0 + wr * 64 + m * 16 + khalf * 4 + j;
          if (slot < rowlim) {
            float v = acc[m][n][j] + bn;
            Hout[(size_t)slot * DH + colg] = f2bf(gelu_tanh(v));
          }
        }
      }
    }
  } else {
#pragma unroll
    for (int m = 0; m < 4; m++) {
#pragma unroll
      for (int j = 0; j < 4; j++) {
        int slot = m0 + wr * 64 + m * 16 + khalf * 4 + j;
        if (slot < rowlim) {
#pragma unroll
          for (int n = 0; n < 4; n++) {
            int colg = nt * 128 + wc * 64 + n * 16 + l15;
            Yout[(size_t)slot * DM + colg] = acc[m][n][j];
          }
        }
      }
    }
  }
#undef STAGE
#undef ITER
}

extern "C" void kernel_launch(void* const* d_in, const int* in_sizes, int n_in,
                              void* d_out, int out_size, void* d_ws, size_t ws_size,
                              hipStream_t stream) {
  const float* x  = (const float*)d_in[0];
  const float* rw = (const float*)d_in[1];
  const float* w1 = (const float*)d_in[2];
  const float* b1 = (const float*)d_in[3];
  const float* w2 = (const float*)d_in[4];
  const float* b2 = (const float*)d_in[5];
  float* out = (float*)d_out;

  char* ws = (char*)d_ws;
  size_t off = 0;
  u16* xbf = (u16*)(ws + off); off += (size_t)T_TOK * DM * 2;
  u16* H   = (u16*)(ws + off); off += (size_t)NSLOT_PAD * DH * 2;
  u16* w1b = (u16*)(ws + off); off += WELEMS * 2;
  u16* w2b = (u16*)(ws + off); off += WELEMS * 2;
  int* tok_map  = (int*)(ws + off); off += (size_t)NSLOT_PAD * 4;
  float* pair_w = (float*)(ws + off); off += (size_t)NSLOT_PAD * 4;
  int* tok_e    = (int*)(ws + off); off += (size_t)T_TOK * 8;
  float* tok_w  = (float*)(ws + off); off += (size_t)T_TOK * 8;
  int* islot    = (int*)(ws + off); off += (size_t)T_TOK * 8;
  int* ctl      = (int*)(ws + off); off += 512;
  // y (fp32, 37.7 MB) overlays w1b (67 MB, dead after fc1 GEMM)
  float* y = (float*)w1b;

  hipMemsetAsync(ctl, 0, 128 * 4, stream);

  router_kernel<<<T_TOK / 4, 256, 0, stream>>>(x, rw, xbf, tok_e, tok_w, ctl);
  scan_kernel<<<1, 128, 0, stream>>>(ctl);
  assign_kernel<<<T_TOK / 256, 256, 0, stream>>>(tok_e, tok_w, ctl, tok_map, pair_w, islot);
  wconv_kernel<<<8192, 256, 0, stream>>>(w1, w2, w1b, w2b);

  moe_gemm<true><<<MAXTILES * (DH / 128), 256, 0, stream>>>(
      xbf, w1b, b1, H, nullptr, tok_map, ctl);
  moe_gemm<false><<<MAXTILES * (DM / 128), 256, 0, stream>>>(
      H, w2b, nullptr, nullptr, y, tok_map, ctl);
  combine_kernel<<<T_TOK * DM / 4 / 256, 256, 0, stream>>>(
      y, b2, tok_e, islot, tok_w, out);
}